// Round 13
// baseline (29.633 us; speedup 1.0000x reference)
//
#include <hip/hip_runtime.h>
#include <math.h>

// Problem constants (from reference setup_inputs)
#define BB 16
#define QQ 900
#define NC 92
#define NCP 96          // padded class count (classes 92..95 have prob 0)
#define TT 1600
#define BQ (BB * QQ)    // 14400

// ---------------------------------------------------------------------------
// R13: R12 algebra + 2-adjacent-targets-per-lane (lean retry of R7).
//   grid = (BQ/8 = 1800, 1), block = 256 = 4 waves, RT=2 rows/wave.
//   12 pair-iters x 128 targets + 64-target scalar tail.
//   Per 4 outputs: 3 VMEM loads, 2 ds_read_b64 gathers, 2 float2 stores
//   (R12: 4 loads, 2 gathers, 4 dword stores) and half the loop control.
//   LDS: normalized probs transposed pg[class][10] (R9 layout, stride 40 B
//   -> 16-bank spread for random ids, b64 fetches both rows, rloc even).
//   GIoU via corrected interval identity (R12):
//     overlap = s - max(|dc|,|dh|), enclose = s + max(|dc|,|dh|).
// ---------------------------------------------------------------------------
#define RT 2        // rows per thread (= rows per wave)
#define RTILE 8     // rows per block
#define NKP 12      // pair iterations: 12 * 128 = 1536, then 64 tail

__global__ __launch_bounds__(256)
void k_cost(const float* __restrict__ logits,
            const float* __restrict__ boxes,       // [BQ,4] cxcywh
            const int* __restrict__ tids,          // [TT] int32
            const float* __restrict__ tbox,        // [TT,4] cxcywh
            float* __restrict__ out) {
    __shared__ float pg[NCP][10];                  // [class][row], 3840 B

    const int row0 = blockIdx.x * RTILE;

    // ---- stage unnormalized exp(logit), transposed; classes 92..95 = 0 ----
    #pragma unroll
    for (int it = 0; it < 3; ++it) {               // 3 x 256 = 768 = 8*96
        int idx = it * 256 + threadIdx.x;
        int r = idx / NCP, c = idx - r * NCP;      // c fast -> coalesced read
        float v = 0.0f;
        if (c < NC) v = __expf(logits[(row0 + r) * NC + c]);
        pg[c][r] = v;
    }
    __syncthreads();

    // ---- normalize in place: thread owns (row r, classes 3ls..3ls+2) ----
    {
        const int r  = threadIdx.x >> 5;           // 0..7
        const int ls = threadIdx.x & 31;           // 0..31 (3*31+2 = 95)
        float a = pg[ls * 3][r];
        float b = pg[ls * 3 + 1][r];
        float d = pg[ls * 3 + 2][r];
        float s = a + b + d;
        s += __shfl_xor(s, 1);
        s += __shfl_xor(s, 2);
        s += __shfl_xor(s, 4);
        s += __shfl_xor(s, 8);
        s += __shfl_xor(s, 16);                    // sum over 32-lane half
        float rinv = __builtin_amdgcn_rcpf(s);
        pg[ls * 3][r]     = a * rinv;
        pg[ls * 3 + 1][r] = b * rinv;
        pg[ls * 3 + 2][r] = d * rinv;
    }

    const int tl   = threadIdx.x & 63;
    const int rg   = threadIdx.x >> 6;
    const int rloc = rg * RT;                      // 0,2,4,6 (b64-aligned)
    const int rbase = row0 + rloc;

    // ---- register-blocked row box data: center + HALF-widths + area ----
    float rcx[RT], rcy[RT], rhw[RT], rhh[RT], rar[RT];
    #pragma unroll
    for (int j = 0; j < RT; ++j) {
        float4 bb = ((const float4*)boxes)[rbase + j];
        rcx[j] = bb.x; rcy[j] = bb.y;
        rhw[j] = 0.5f * bb.z; rhh[j] = 0.5f * bb.w;
        rar[j] = bb.z * bb.w;
    }
    __syncthreads();

    const float4* tb4 = (const float4*)tbox;
    const int2*   id2 = (const int2*)tids;

    // ---- main loop: 12 iters x 128 targets (2 adjacent per lane) ----
    float4 ta = tb4[2 * tl];
    float4 tc = tb4[2 * tl + 1];
    int2   ii = id2[tl];
    #pragma unroll 4
    for (int k = 0; k < NKP; ++k) {
        const int tp = k * 64 + tl;                // pair index
        float4 tan, tcn; int2 iin;
        if (k + 1 < NKP) {
            tan = tb4[2 * (tp + 64)];
            tcn = tb4[2 * (tp + 64) + 1];
            iin = id2[tp + 64];
        }
        // gathers: one b64 per target covers both rows
        float2 pa = *(const float2*)&pg[ii.x][rloc];
        float2 pc = *(const float2*)&pg[ii.y][rloc];
        float ahw = 0.5f * ta.z, ahh = 0.5f * ta.w, aar = ta.z * ta.w;
        float chw = 0.5f * tc.z, chh = 0.5f * tc.w, car = tc.z * tc.w;

        #pragma unroll
        for (int j = 0; j < RT; ++j) {
            float2 o;
            {   // target a
                float dx = rcx[j] - ta.x, dy = rcy[j] - ta.y;
                float dw = rhw[j] - ahw,  dh = rhh[j] - ahh;
                float a1 = fabsf(dx) + fabsf(dy);
                float a2 = fabsf(dw) + fabsf(dh);
                float l1 = fmaf(2.0f, a2, a1);
                float mx = fmaxf(fabsf(dx), fabsf(dw));
                float my = fmaxf(fabsf(dy), fabsf(dh));
                float sx = rhw[j] + ahw, sy = rhh[j] + ahh;
                float inter = fmaxf(sx - mx, 0.0f) * fmaxf(sy - my, 0.0f);
                float uni = (rar[j] + aar) - inter;
                float ea = (sx + mx) * (sy + my);
                float num = fmaf(ea, inter - uni, uni * uni);
                float rden = __builtin_amdgcn_rcpf(uni * ea);
                float p = (j == 0) ? pa.x : pa.y;
                float c = fmaf(5.0f, l1, -p);
                o.x = fmaf(-2.0f * num, rden, c);
            }
            {   // target c
                float dx = rcx[j] - tc.x, dy = rcy[j] - tc.y;
                float dw = rhw[j] - chw,  dh = rhh[j] - chh;
                float a1 = fabsf(dx) + fabsf(dy);
                float a2 = fabsf(dw) + fabsf(dh);
                float l1 = fmaf(2.0f, a2, a1);
                float mx = fmaxf(fabsf(dx), fabsf(dw));
                float my = fmaxf(fabsf(dy), fabsf(dh));
                float sx = rhw[j] + chw, sy = rhh[j] + chh;
                float inter = fmaxf(sx - mx, 0.0f) * fmaxf(sy - my, 0.0f);
                float uni = (rar[j] + car) - inter;
                float ea = (sx + mx) * (sy + my);
                float num = fmaf(ea, inter - uni, uni * uni);
                float rden = __builtin_amdgcn_rcpf(uni * ea);
                float p = (j == 0) ? pc.x : pc.y;
                float c = fmaf(5.0f, l1, -p);
                o.y = fmaf(-2.0f * num, rden, c);
            }
            *(float2*)&out[(rbase + j) * TT + 2 * tp] = o;
        }
        ta = tan; tc = tcn; ii = iin;
    }

    // ---- tail: targets 1536..1599, one per lane (R12 inner) ----
    {
        const int t = NKP * 128 + tl;
        float4 tb = tb4[t];
        int    id = tids[t];
        float2 pp = *(const float2*)&pg[id][rloc];
        float thw = 0.5f * tb.z, thh = 0.5f * tb.w, tar = tb.z * tb.w;
        #pragma unroll
        for (int j = 0; j < RT; ++j) {
            float dx = rcx[j] - tb.x, dy = rcy[j] - tb.y;
            float dw = rhw[j] - thw,  dh = rhh[j] - thh;
            float a1 = fabsf(dx) + fabsf(dy);
            float a2 = fabsf(dw) + fabsf(dh);
            float l1 = fmaf(2.0f, a2, a1);
            float mx = fmaxf(fabsf(dx), fabsf(dw));
            float my = fmaxf(fabsf(dy), fabsf(dh));
            float sx = rhw[j] + thw, sy = rhh[j] + thh;
            float inter = fmaxf(sx - mx, 0.0f) * fmaxf(sy - my, 0.0f);
            float uni = (rar[j] + tar) - inter;
            float ea = (sx + mx) * (sy + my);
            float num = fmaf(ea, inter - uni, uni * uni);
            float rden = __builtin_amdgcn_rcpf(uni * ea);
            float p = (j == 0) ? pp.x : pp.y;
            float c = fmaf(5.0f, l1, -p);
            c = fmaf(-2.0f * num, rden, c);
            out[(rbase + j) * TT + t] = c;
        }
    }
}

// ---------------------------------------------------------------------------
extern "C" void kernel_launch(void* const* d_in, const int* in_sizes, int n_in,
                              void* d_out, int out_size, void* d_ws, size_t ws_size,
                              hipStream_t stream) {
    const float* logits = (const float*)d_in[0];   // [16,900,92] f32
    const float* boxes  = (const float*)d_in[1];   // [16,900,4]  f32
    const int*   tids   = (const int*)  d_in[2];   // [1600] int32
    const float* tbox   = (const float*)d_in[3];   // [1600,4] f32
    float* out = (float*)d_out;

    k_cost<<<dim3(BQ / RTILE, 1), 256, 0, stream>>>(
        logits, boxes, tids, tbox, out);
}

// Round 14
// 27.173 us; speedup vs baseline: 1.0905x; 1.0905x over previous
//
#include <hip/hip_runtime.h>
#include <math.h>

// Problem constants (from reference setup_inputs)
#define BB 16
#define QQ 900
#define NC 92
#define NCP 96          // padded LDS row
#define TT 1600
#define BQ (BB * QQ)    // 14400

// ---------------------------------------------------------------------------
// R14: R12 (best, 27.1 us) with the main loop FULLY unrolled.
//   grid = (BQ/8 = 1800, 1), block = 256 = 4 waves, RT=2, full target sweep.
//   GIoU via corrected interval identity (R12):
//     overlap = (h1+h2) - max(|dc|,|dh|), enclose = (h1+h2) + max(|dc|,|dh|)
//   Full unroll removes per-iter loop control (~6 instrs/iter) and lets the
//   scheduler interleave loads/stores across all 25 iterations.
// ---------------------------------------------------------------------------
#define RT 2        // rows per thread (= rows per wave)
#define RTILE 8     // rows per block
#define NK 25       // 25 x 64 targets = 1600

__global__ __launch_bounds__(256)
void k_cost(const float* __restrict__ logits,
            const float* __restrict__ boxes,       // [BQ,4] cxcywh
            const int* __restrict__ tids,          // [TT] int32
            const float* __restrict__ tbox,        // [TT,4] cxcywh
            float* __restrict__ out) {
    __shared__ float pexp[RTILE][NCP];             // 3072 B

    const int row0 = blockIdx.x * RTILE;

    // ---- stage unnormalized exp(logit) via float2; pad cols 92..95 = 0 ----
    {
        int idx = threadIdx.x * 2;
        int r = idx / NCP, c = idx - r * NCP;
        float2 v = make_float2(0.0f, 0.0f);
        if (c < NC) {
            float2 lv = *(const float2*)&logits[(row0 + r) * NC + c];
            v.x = __expf(lv.x); v.y = __expf(lv.y);
        }
        *(float2*)&pexp[r][c] = v;
        if (threadIdx.x < 128) {
            int idx2 = 512 + threadIdx.x * 2;
            int r2 = idx2 / NCP, c2 = idx2 - r2 * NCP;
            float2 v2 = make_float2(0.0f, 0.0f);
            if (c2 < NC) {
                float2 lv = *(const float2*)&logits[(row0 + r2) * NC + c2];
                v2.x = __expf(lv.x); v2.y = __expf(lv.y);
            }
            *(float2*)&pexp[r2][c2] = v2;
        }
    }
    __syncthreads();

    // ---- normalize LDS probs in place (stride-3 cols, conflict-free) ----
    {
        const int r  = threadIdx.x >> 5;           // 0..7
        const int ls = threadIdx.x & 31;           // 0..31
        float a = pexp[r][ls * 3];
        float b = pexp[r][ls * 3 + 1];
        float d = pexp[r][ls * 3 + 2];
        float s = a + b + d;
        s += __shfl_xor(s, 1);
        s += __shfl_xor(s, 2);
        s += __shfl_xor(s, 4);
        s += __shfl_xor(s, 8);
        s += __shfl_xor(s, 16);
        float rinv = __builtin_amdgcn_rcpf(s);
        pexp[r][ls * 3]     = a * rinv;
        pexp[r][ls * 3 + 1] = b * rinv;
        pexp[r][ls * 3 + 2] = d * rinv;
    }

    const int tl   = threadIdx.x & 63;
    const int rg   = threadIdx.x >> 6;
    const int rloc = rg * RT;
    const int rbase = row0 + rloc;

    // ---- register-blocked row box data: center + HALF-widths + area ----
    float rcx[RT], rcy[RT], rhw[RT], rhh[RT], rar[RT];
    #pragma unroll
    for (int j = 0; j < RT; ++j) {
        float4 bb = ((const float4*)boxes)[rbase + j];
        rcx[j] = bb.x; rcy[j] = bb.y;
        rhw[j] = 0.5f * bb.z; rhh[j] = 0.5f * bb.w;
        rar[j] = bb.z * bb.w;
    }
    __syncthreads();

    // ---- main loop: 25 x 64 targets, FULL unroll, prefetch, plain stores ----
    float* o0 = out + rbase * TT + tl;
    float4 tb = ((const float4*)tbox)[tl];
    int    id = tids[tl];
    #pragma unroll
    for (int k = 0; k < NK; ++k) {
        float4 tbn; int idn;
        if (k + 1 < NK) {
            tbn = ((const float4*)tbox)[(k + 1) * 64 + tl];
            idn = tids[(k + 1) * 64 + tl];
        }
        float thw = 0.5f * tb.z, thh = 0.5f * tb.w;
        float tar = tb.z * tb.w;
        #pragma unroll
        for (int j = 0; j < RT; ++j) {
            // center / half-width diffs (abs folds as VOP3 input modifier)
            float dx = rcx[j] - tb.x;
            float dy = rcy[j] - tb.y;
            float dw = rhw[j] - thw;               // half of (rw - tw)
            float dh = rhh[j] - thh;
            // L1 = |dx|+|dy|+2(|dw|+|dh|)
            float a1 = fabsf(dx) + fabsf(dy);
            float a2 = fabsf(dw) + fabsf(dh);
            float l1 = fmaf(2.0f, a2, a1);
            // general interval identity:
            //   overlap = s - max(|dc|,|dh|),  enclose = s + max(|dc|,|dh|)
            float mx = fmaxf(fabsf(dx), fabsf(dw));
            float my = fmaxf(fabsf(dy), fabsf(dh));
            float sx = rhw[j] + thw;
            float sy = rhh[j] + thh;
            float iwu = sx - mx;
            float ihu = sy - my;
            float ew  = sx + mx;
            float eh  = sy + my;
            float inter = fmaxf(iwu, 0.0f) * fmaxf(ihu, 0.0f);
            float uni = (rar[j] + tar) - inter;
            float ea = ew * eh;
            // giou = (ea*(inter-uni) + uni^2) / (uni*ea), single rcp
            float num = fmaf(ea, inter - uni, uni * uni);
            float rden = __builtin_amdgcn_rcpf(uni * ea);
            // C = 5*l1 - p - 2*giou
            float p = pexp[rloc + j][id];
            float c = fmaf(5.0f, l1, -p);
            c = fmaf(-2.0f * num, rden, c);
            o0[j * TT + k * 64] = c;
        }
        tb = tbn; id = idn;
    }
}

// ---------------------------------------------------------------------------
extern "C" void kernel_launch(void* const* d_in, const int* in_sizes, int n_in,
                              void* d_out, int out_size, void* d_ws, size_t ws_size,
                              hipStream_t stream) {
    const float* logits = (const float*)d_in[0];   // [16,900,92] f32
    const float* boxes  = (const float*)d_in[1];   // [16,900,4]  f32
    const int*   tids   = (const int*)  d_in[2];   // [1600] int32
    const float* tbox   = (const float*)d_in[3];   // [1600,4] f32
    float* out = (float*)d_out;

    k_cost<<<dim3(BQ / RTILE, 1), 256, 0, stream>>>(
        logits, boxes, tids, tbox, out);
}